// Round 13
// baseline (356.562 us; speedup 1.0000x reference)
//
#include <hip/hip_runtime.h>

#define NB   64
#define NT   30
#define NBT  1920        // NB*NT
#define EE   128
#define KP   28224       // 4*84*84
#define LTK  89          // 3*NT-1
#define NS   5696        // NB*LTK
#define NLY  6
#define NV   18
#define NZ   21          // split-K slabs for patch gemm

typedef unsigned short ushort_t;
using bf16x8 = __attribute__((ext_vector_type(8))) short;
using us8    = __attribute__((ext_vector_type(8))) unsigned short;
using f32x4  = __attribute__((ext_vector_type(4))) float;
using f32x16 = __attribute__((ext_vector_type(16))) float;

__device__ inline ushort_t f2bf(float f){
  union { float f; unsigned u; } v; v.f = f;
  unsigned r = v.u + 0x7FFFu + ((v.u >> 16) & 1u);   // RNE
  return (ushort_t)(r >> 16);
}
__device__ inline float bf2f(ushort_t h){
  union { unsigned u; float f; } v; v.u = ((unsigned)h) << 16; return v.f;
}

// ==== patch embed + weight conversion, ONE dispatch (role-split blocks) ====
// blocks [0,630): patch gemm (reads conv_w fp32 directly, converts in-reg)
// blocks [630,1878): fp32->bf16 conversion of remaining weights
// blocks [1878,1881): qkv bias pack
__global__ __launch_bounds__(256) void patch_conv(
  const float* __restrict__ A, const float* __restrict__ convW,
  const float* Wq, const float* Wk, const float* Wv,
  const float* Wo, const float* W1, const float* W2,
  const float* in_w, const float* out_w, const float* f1w, const float* f2w,
  const float* bq, const float* bk, const float* bv,
  ushort_t* dqkv, ushort_t* dout, ushort_t* d1, ushort_t* d2,
  ushort_t* dinw, ushort_t* doutw, ushort_t* df1, ushort_t* df2,
  float* bqkv, float* __restrict__ C)
{
  __shared__ __align__(16) ushort_t As[2][64*64];
  __shared__ __align__(16) ushort_t Ws[2][128*64];
  const int bx = blockIdx.x, tid = threadIdx.x;

  if (bx >= 630){
    if (bx >= 1878){                      // bias-pack tail
      int idx = (bx-1878)*256 + tid;
      if (idx < NLY*128){ int l=idx>>7, j=idx&127;
        bqkv[l*384+j]=bq[idx]; bqkv[l*384+128+j]=bk[idx]; bqkv[l*384+256+j]=bv[idx]; }
      return;
    }
    long i = 4l*((long)(bx-630)*256 + tid) + 3612672l;
    if (i < 3907584l){                    // Wq | Wk | Wv  ->  (L,384,128)
      long o = i - 3612672l;
      int  seg = (int)(o / 98304l);
      long off2 = o - (long)seg*98304l;
      long layer = off2 >> 14, rem = off2 & 16383l;
      const float* s = (seg==0) ? Wq : (seg==1) ? Wk : Wv;
      float4 f = *reinterpret_cast<const float4*>(s+off2);
      long dst = layer*49152l + (long)seg*16384l + rem;
      dqkv[dst]=f2bf(f.x); dqkv[dst+1]=f2bf(f.y); dqkv[dst+2]=f2bf(f.z); dqkv[dst+3]=f2bf(f.w);
      return;
    }
    const float* s; ushort_t* d; long off;
    if      (i < 4005888l){ s=Wo;    d=dout;  off=i-3907584l; }
    else if (i < 4399104l){ s=W1;    d=d1;    off=i-4005888l; }
    else if (i < 4792320l){ s=W2;    d=d2;    off=i-4399104l; }
    else if (i < 4841472l){ s=in_w;  d=dinw;  off=i-4792320l; }
    else if (i < 4857856l){ s=out_w; d=doutw; off=i-4841472l; }
    else if (i < 4874240l){ s=f1w;   d=df1;   off=i-4857856l; }
    else                  { s=f2w;   d=df2;   off=i-4874240l; }
    float4 f = *reinterpret_cast<const float4*>(s+off);
    d[off]=f2bf(f.x); d[off+1]=f2bf(f.y); d[off+2]=f2bf(f.z); d[off+3]=f2bf(f.w);
    return;
  }

  // ---------------- patch role: BM=64, z-slab split-K --------------------
  const int mb = bx / NZ, z = bx - mb*NZ;
  const int lane = tid & 63, wid = tid >> 6;
  const int m0 = mb * 64;
  const int kbase = z * 1344;
  float* Cz = C + (size_t)z * NBT * EE;
  const int ra = tid>>2, ca = (tid&3)*16, swa = (ra&7)<<3;
  const int rw = tid>>1, cw = (tid&1)*32, sww = (rw&7)<<3;
  const float* Ab = A     + (size_t)(m0+ra)*KP + kbase + ca;
  const float* Wf = convW + (size_t)rw*KP     + kbase + cw;
  f32x4 acc[8];
  #pragma unroll
  for (int j=0;j<8;j++) acc[j] = (f32x4){0.f,0.f,0.f,0.f};

  auto loadT = [&](float4 (&fa)[4], float4 (&wf)[8], int kt){
    #pragma unroll
    for (int q=0;q<4;q++) fa[q] = *reinterpret_cast<const float4*>(Ab + kt*64 + 4*q);
    #pragma unroll
    for (int q=0;q<8;q++) wf[q] = *reinterpret_cast<const float4*>(Wf + kt*64 + 4*q);
  };
  auto commitT = [&](int buf, const float4 (&fa)[4], const float4 (&wf)[8]){
    us8 o0, o1;
    o0[0]=f2bf(fa[0].x); o0[1]=f2bf(fa[0].y); o0[2]=f2bf(fa[0].z); o0[3]=f2bf(fa[0].w);
    o0[4]=f2bf(fa[1].x); o0[5]=f2bf(fa[1].y); o0[6]=f2bf(fa[1].z); o0[7]=f2bf(fa[1].w);
    o1[0]=f2bf(fa[2].x); o1[1]=f2bf(fa[2].y); o1[2]=f2bf(fa[2].z); o1[3]=f2bf(fa[2].w);
    o1[4]=f2bf(fa[3].x); o1[5]=f2bf(fa[3].y); o1[6]=f2bf(fa[3].z); o1[7]=f2bf(fa[3].w);
    *reinterpret_cast<us8*>(&As[buf][ra*64 + ( ca    ^ swa)]) = o0;
    *reinterpret_cast<us8*>(&As[buf][ra*64 + ((ca+8) ^ swa)]) = o1;
    #pragma unroll
    for (int q=0;q<4;q++){
      us8 ow;
      float4 wA = wf[2*q], wB = wf[2*q+1];
      ow[0]=f2bf(wA.x); ow[1]=f2bf(wA.y); ow[2]=f2bf(wA.z); ow[3]=f2bf(wA.w);
      ow[4]=f2bf(wB.x); ow[5]=f2bf(wB.y); ow[6]=f2bf(wB.z); ow[7]=f2bf(wB.w);
      *reinterpret_cast<us8*>(&Ws[buf][rw*64 + ((cw+8*q) ^ sww)]) = ow;
    }
  };
  auto computeT = [&](int buf){
    #pragma unroll
    for (int ks=0; ks<2; ++ks){
      int arow = wid*16 + (lane&15);
      int kb = ks*32 + (lane>>4)*8;
      bf16x8 a = *reinterpret_cast<const bf16x8*>(&As[buf][arow*64 + (kb ^ ((arow&7)<<3))]);
      #pragma unroll
      for (int nt=0; nt<8; ++nt){
        int nn = nt*16 + (lane&15);
        bf16x8 b = *reinterpret_cast<const bf16x8*>(&Ws[buf][nn*64 + (kb ^ ((nn&7)<<3))]);
        acc[nt] = __builtin_amdgcn_mfma_f32_16x16x32_bf16(a, b, acc[nt], 0,0,0);
      }
    }
  };

  float4 faA[4], faB[4], wfA[8], wfB[8];
  loadT(faA, wfA, 0);
  loadT(faB, wfB, 1);
  for (int kp = 0; kp < 11; ++kp){
    int kt0 = 2*kp;
    commitT(0, faA, wfA);
    if (kt0 + 2 < 21) loadT(faA, wfA, kt0 + 2);
    __syncthreads();
    computeT(0);
    int kt1 = kt0 + 1;
    if (kt1 < 21){
      commitT(1, faB, wfB);
      if (kt1 + 2 < 21) loadT(faB, wfB, kt1 + 2);
      __syncthreads();
      computeT(1);
    }
  }
  #pragma unroll
  for (int nt=0; nt<8; ++nt)
    #pragma unroll
    for (int rr=0;rr<4;rr++){
      int row = m0 + wid*16 + (lane>>4)*4 + rr;
      int col = nt*16 + (lane&15);
      Cz[row*EE + col] = acc[nt][rr];
    }
}

// ======= inner TIT v3: 8 bt/block, 76.6KB LDS -> 2 blocks/CU ===============
__global__ __launch_bounds__(256, 2) void inner_tit(
  const float* __restrict__ part, const float* __restrict__ ctok,
  const ushort_t* __restrict__ inw, const float* __restrict__ in_b,
  const ushort_t* __restrict__ outw, const float* __restrict__ out_b,
  const float* __restrict__ g1, const float* __restrict__ b1_,
  const float* __restrict__ g2, const float* __restrict__ b2_,
  const ushort_t* __restrict__ f1wb, const float* __restrict__ fb1,
  const ushort_t* __restrict__ f2wb, const float* __restrict__ fb2,
  const float* __restrict__ rtgs, const int* __restrict__ actions,
  const int* __restrict__ tsteps, const float* __restrict__ ret_w,
  const float* __restrict__ ret_b, const float* __restrict__ act_tab,
  const float* __restrict__ pos_emb, const float* __restrict__ gpos,
  const float* __restrict__ ln1g0, const float* __restrict__ ln1b0,
  float* __restrict__ x, ushort_t* __restrict__ xln)
{
  __shared__ __align__(16) ushort_t wbuf[192*128];   // 48K
  __shared__ float xs[16*128];                        // 8K
  __shared__ __align__(16) ushort_t hb[16*128];      // 4K
  __shared__ __align__(16) ushort_t hf[16*128];      // 4K
  __shared__ __align__(16) ushort_t qkvb[16*400];    // 12.5K bf16
  __shared__ float ssm[32];
  const int tid = threadIdx.x, lane = tid & 63, wid = tid >> 6;
  const int bt0 = blockIdx.x * 8;

  auto stageWB = [&](const ushort_t* src, int R){
    for (int c = tid; c < R*16; c += 256){
      int rr = c >> 4, cc = (c & 15) * 8;
      *reinterpret_cast<us8*>(&wbuf[rr*128 + (cc ^ ((rr&7)<<3))]) =
        *reinterpret_cast<const us8*>(src + (size_t)rr*128 + cc);
    }
  };
  auto lnrow = [&](const float* gam, const float* bet, ushort_t* dst){
    int r = tid >> 4, e0 = (tid & 15) * 8;
    float v[8];
    #pragma unroll
    for (int j=0;j<8;j++) v[j] = xs[r*128 + e0 + j];
    float s = 0;
    #pragma unroll
    for (int j=0;j<8;j++) s += v[j];
    s += __shfl_xor(s,1); s += __shfl_xor(s,2); s += __shfl_xor(s,4); s += __shfl_xor(s,8);
    float mean = s * (1.0f/128.0f);
    float vs = 0;
    #pragma unroll
    for (int j=0;j<8;j++){ float d = v[j]-mean; vs += d*d; }
    vs += __shfl_xor(vs,1); vs += __shfl_xor(vs,2); vs += __shfl_xor(vs,4); vs += __shfl_xor(vs,8);
    float rstd = rsqrtf(vs*(1.0f/128.0f) + 1e-5f);
    us8 o;
    #pragma unroll
    for (int j=0;j<8;j++) o[j] = f2bf((v[j]-mean)*rstd*gam[e0+j] + bet[e0+j]);
    *reinterpret_cast<us8*>(&dst[r*128 + (e0 ^ ((r&7)<<3))]) = o;
  };
  auto qgemm = [&](const ushort_t* abuf, int ntg, int rowoff, f32x4& acc){
    int al = lane & 15, kq = (lane>>4)*8;
    int nrow = (ntg*16 + al) - rowoff, nsw = (nrow&7)<<3;
    #pragma unroll
    for (int ks=0; ks<4; ++ks){
      int kb = ks*32 + kq;
      bf16x8 a = *reinterpret_cast<const bf16x8*>(&abuf[al*128 + (kb ^ ((al&7)<<3))]);
      bf16x8 b = *reinterpret_cast<const bf16x8*>(&wbuf[nrow*128 + (kb ^ nsw)]);
      acc = __builtin_amdgcn_mfma_f32_16x16x32_bf16(a, b, acc, 0,0,0);
    }
  };

  { int r = tid >> 4, e0 = (tid & 15) * 8;
    float v[8];
    if ((r & 1) == 0){
      #pragma unroll
      for (int j=0;j<8;j++) v[j] = ctok[e0+j];
    } else {
      #pragma unroll
      for (int j=0;j<8;j++) v[j] = 0.f;
      int bt = bt0 + (r>>1);
      for (int z=0; z<NZ; ++z){
        const float* p = part + (size_t)z*NBT*EE + (size_t)bt*128 + e0;
        float4 f0 = *reinterpret_cast<const float4*>(p);
        float4 f1 = *reinterpret_cast<const float4*>(p+4);
        v[0]+=f0.x; v[1]+=f0.y; v[2]+=f0.z; v[3]+=f0.w;
        v[4]+=f1.x; v[5]+=f1.y; v[6]+=f1.z; v[7]+=f1.w;
      }
    }
    #pragma unroll
    for (int j=0;j<8;j++) xs[r*128 + e0 + j] = v[j];
  }
  stageWB(inw, 192);
  __syncthreads();

  lnrow(g1, b1_, hb);
  __syncthreads();

  { int al = lane & 15;
    #pragma unroll
    for (int j=0;j<3;++j){
      int nt = wid*3 + j;
      f32x4 acc = (f32x4){0.f,0.f,0.f,0.f};
      qgemm(hb, nt, 0, acc);
      float bia = in_b[nt*16 + al];
      #pragma unroll
      for (int rr=0; rr<4; ++rr){
        int row = (lane>>4)*4 + rr;
        qkvb[row*400 + nt*16 + al] = f2bf(acc[rr] + bia);
      }
    }
  }
  __syncthreads();
  stageWB(inw + (size_t)192*128, 192);
  __syncthreads();
  { int al = lane & 15;
    #pragma unroll
    for (int j=0;j<3;++j){
      int nt = 12 + wid*3 + j;
      f32x4 acc = (f32x4){0.f,0.f,0.f,0.f};
      qgemm(hb, nt, 192, acc);
      float bia = in_b[nt*16 + al];
      #pragma unroll
      for (int rr=0; rr<4; ++rr){
        int row = (lane>>4)*4 + rr;
        qkvb[row*400 + nt*16 + al] = f2bf(acc[rr] + bia);
      }
    }
  }
  __syncthreads();

  { int d = tid >> 3, j = tid & 7;
    int i = d >> 2, p = d & 3;
    const ushort_t* qp = &qkvb[(2*i + (p>>1))*400 + j*16];
    const ushort_t* kp = &qkvb[(2*i + (p&1))*400 + 128 + j*16];
    float s = 0;
    #pragma unroll
    for (int e=0;e<16;e++) s += bf2f(qp[e])*bf2f(kp[e]);
    s += __shfl_xor(s,1); s += __shfl_xor(s,2); s += __shfl_xor(s,4);
    if (j == 0) ssm[d] = s;
  }
  stageWB(outw, 128);
  __syncthreads();

  { int r = tid >> 4, e0 = (tid & 15)*8;
    int i = r >> 1, t = r & 1;
    const float sc = 0.08838834764831845f;
    float s0 = ssm[i*4 + t*2]*sc, s1 = ssm[i*4 + t*2 + 1]*sc;
    float m = fmaxf(s0,s1), p0 = __expf(s0-m), p1 = __expf(s1-m);
    float iv = 1.0f/(p0+p1); p0 *= iv; p1 *= iv;
    const ushort_t* v0 = &qkvb[(2*i)*400 + 256 + e0];
    const ushort_t* v1 = &qkvb[(2*i+1)*400 + 256 + e0];
    us8 o;
    #pragma unroll
    for (int j=0;j<8;j++) o[j] = f2bf(p0*bf2f(v0[j]) + p1*bf2f(v1[j]));
    *reinterpret_cast<us8*>(&hb[r*128 + (e0 ^ ((r&7)<<3))]) = o;
  }
  __syncthreads();

  { int al = lane & 15;
    #pragma unroll
    for (int j=0;j<2;++j){
      int nt = wid*2 + j;
      f32x4 acc = (f32x4){0.f,0.f,0.f,0.f};
      qgemm(hb, nt, 0, acc);
      float bia = out_b[nt*16 + al];
      #pragma unroll
      for (int rr=0; rr<4; ++rr){
        int row = (lane>>4)*4 + rr;
        xs[row*128 + nt*16 + al] += acc[rr] + bia;
      }
    }
  }
  __syncthreads();

  lnrow(g2, b2_, hb);
  stageWB(f1wb, 128);
  __syncthreads();

  { int al = lane & 15;
    #pragma unroll
    for (int j=0;j<2;++j){
      int nt = wid*2 + j;
      f32x4 acc = (f32x4){0.f,0.f,0.f,0.f};
      qgemm(hb, nt, 0, acc);
      float bia = fb1[nt*16 + al];
      #pragma unroll
      for (int rr=0; rr<4; ++rr){
        int row = (lane>>4)*4 + rr;
        hf[row*128 + ((nt*16+al) ^ ((row&7)<<3))] = f2bf(fmaxf(acc[rr] + bia, 0.f));
      }
    }
  }
  __syncthreads();

  stageWB(f2wb, 128);
  __syncthreads();
  { int al = lane & 15;
    #pragma unroll
    for (int j=0;j<2;++j){
      int nt = wid*2 + j;
      f32x4 acc = (f32x4){0.f,0.f,0.f,0.f};
      qgemm(hf, nt, 0, acc);
      float bia = fb2[nt*16 + al];
      #pragma unroll
      for (int rr=0; rr<4; ++rr){
        int row = (lane>>4)*4 + rr;
        xs[row*128 + nt*16 + al] += acc[rr] + bia;
      }
    }
  }
  __syncthreads();

  { int q = tid >> 3, j = tid & 7;
    if (q < 24){
      int i = q / 3, kind = q - 3*i;
      int btg = bt0 + i, b = btg / NT, t = btg - b*NT;
      bool valid = !(kind == 2 && t == 0);
      if (valid){
        int prow = (kind==0) ? 3*t : (kind==1) ? 3*t+1 : 3*t-1;
        size_t xrow = ((size_t)b*LTK + prow)*128;
        int ts = tsteps[b];
        int e0 = j*16;
        float v[16];
        if (kind == 1){
          #pragma unroll
          for (int e=0;e<16;e++) v[e] = xs[(2*i)*128 + e0 + e];
        } else if (kind == 0){
          float rv = rtgs[b*NT+t];
          #pragma unroll
          for (int e=0;e<16;e++) v[e] = tanhf(rv*ret_w[e0+e] + ret_b[e0+e]);
        } else {
          int a = actions[b*NT+t];
          #pragma unroll
          for (int e=0;e<16;e++) v[e] = tanhf(act_tab[a*128 + e0 + e]);
        }
        #pragma unroll
        for (int e=0;e<16;e++)
          v[e] += gpos[(size_t)ts*128 + e0 + e] + pos_emb[prow*128 + e0 + e];
        #pragma unroll
        for (int e=0;e<16;e++) x[xrow + e0 + e] = v[e];
        float s = 0;
        #pragma unroll
        for (int e=0;e<16;e++) s += v[e];
        s += __shfl_xor(s,1); s += __shfl_xor(s,2); s += __shfl_xor(s,4);
        float mean = s * (1.0f/128.0f);
        float vs = 0;
        #pragma unroll
        for (int e=0;e<16;e++){ float d = v[e]-mean; vs += d*d; }
        vs += __shfl_xor(vs,1); vs += __shfl_xor(vs,2); vs += __shfl_xor(vs,4);
        float rstd = rsqrtf(vs*(1.0f/128.0f) + 1e-5f);
        #pragma unroll
        for (int e=0;e<16;e++)
          xln[xrow + e0 + e] = f2bf((v[e]-mean)*rstd*ln1g0[e0+e] + ln1b0[e0+e]);
      }
    }
  }
}

// ======== fused attention: one block per (b,h); reads pre-LN'd xln =========
__global__ __launch_bounds__(256, 2) void attn_fused(
  const ushort_t* __restrict__ xln, const ushort_t* __restrict__ Wqkv,
  const float* __restrict__ bqkv, ushort_t* __restrict__ y)
{
  __shared__ __align__(16) char sm[69504];
  ushort_t* ab  = (ushort_t*)sm;              // [96][128] bf16 swz (24576)
  ushort_t* wb  = (ushort_t*)(sm + 24576);    // [48][128] bf16 swz (12288)
  float*    S   = (float*)sm;                 // [96][97] f32 union ab/wb
  ushort_t* qa  = (ushort_t*)(sm + 37248);    // [96][22] bf16
  ushort_t* ka  = (ushort_t*)(sm + 41472);    // [96][22]
  ushort_t* vta = (ushort_t*)(sm + 45696);    // [16][108] V^T
  ushort_t* pb  = (ushort_t*)(sm + 49152);    // [96][104]
  float*    inv = (float*)(sm + 69120);       // [96]

  const int b = blockIdx.x >> 3, h = blockIdx.x & 7;
  const int tid = threadIdx.x, lane = tid & 63, wid = tid >> 6;

  for (int idx = tid; idx < 1536; idx += 256){
    int row = idx >> 4, c0 = (idx & 15) * 8;
    us8 v;
    if (row < LTK) v = *reinterpret_cast<const us8*>(xln + ((size_t)(b*LTK+row))*128 + c0);
    else           v = (us8){0,0,0,0,0,0,0,0};
    *reinterpret_cast<us8*>(&ab[row*128 + (c0 ^ ((row&7)<<3))]) = v;
  }
  for (int idx = tid; idx < 384; idx += 256){
    int rr = idx >> 3, c = (idx & 7) * 16;
    int seg = rr >> 4, n = rr & 15;
    const ushort_t* src = Wqkv + (size_t)(seg*128 + h*16 + n)*128 + c;
    int sw = (rr&7)<<3;
    *reinterpret_cast<us8*>(&wb[rr*128 + ( c    ^ sw)]) = *reinterpret_cast<const us8*>(src);
    *reinterpret_cast<us8*>(&wb[rr*128 + ((c+8) ^ sw)]) = *reinterpret_cast<const us8*>(src+8);
  }
  __syncthreads();

  for (int idx = wid; idx < 18; idx += 4){
    int rt = idx / 3, nt = idx - 3*(idx/3);
    f32x4 acc = (f32x4){0.f,0.f,0.f,0.f};
    int arow = rt*16 + (lane&15), asw = (arow&7)<<3;
    int nrow = nt*16 + (lane&15), nsw = (nrow&7)<<3;
    #pragma unroll
    for (int ks=0; ks<4; ++ks){
      int kb = ks*32 + (lane>>4)*8;
      bf16x8 a = *reinterpret_cast<const bf16x8*>(&ab[arow*128 + (kb ^ asw)]);
      bf16x8 bf = *reinterpret_cast<const bf16x8*>(&wb[nrow*128 + (kb ^ nsw)]);
      acc = __builtin_amdgcn_mfma_f32_16x16x32_bf16(a, bf, acc, 0,0,0);
    }
    int d = lane & 15;
    float bia = bqkv[nt*128 + h*16 + d];
    #pragma unroll
    for (int rr=0; rr<4; ++rr){
      int rg = rt*16 + (lane>>4)*4 + rr;
      ushort_t hv = f2bf(acc[rr] + bia);
      if      (nt == 0) qa[rg*22 + d] = hv;
      else if (nt == 1) ka[rg*22 + d] = hv;
      else              vta[d*108 + rg] = hv;
    }
  }
  __syncthreads();

  {
    static const int TR[6] = {0,1,1,2,2,2};
    static const int TC[6] = {0,0,1,0,1,2};
    for (int idx = wid; idx < 6; idx += 4){
      int R = TR[idx], C = TC[idx];
      int arow = R*32 + (lane&31), brow = C*32 + (lane&31);
      int ke = (lane>>5)*8;
      bf16x8 a  = *reinterpret_cast<const bf16x8*>(&qa[arow*22 + ke]);
      bf16x8 bf = *reinterpret_cast<const bf16x8*>(&ka[brow*22 + ke]);
      f32x16 sc = {};
      sc = __builtin_amdgcn_mfma_f32_32x32x16_bf16(a, bf, sc, 0,0,0);
      #pragma unroll
      for (int r=0; r<16; ++r){
        int rin = (r&3) + 8*(r>>2) + 4*(lane>>5);
        S[(R*32+rin)*97 + C*32 + (lane&31)] = sc[r]*0.25f;
      }
    }
  }
  __syncthreads();

  if (tid < 192){
    int t = tid >> 1, half = tid & 1;
    int u0 = half*48;
    float mx = -1e30f;
    if (t < LTK){
      for (int u=u0; u<u0+48; ++u) if (u<=t) mx = fmaxf(mx, S[t*97+u]);
    }
    mx = fmaxf(mx, __shfl_xor(mx,1));
    float smv = 0;
    if (t < LTK){
      for (int u=u0; u<u0+48; ++u){
        float p = 0;
        if (u<=t){ p = __expf(S[t*97+u]-mx); smv += p; }
        pb[t*104+u] = f2bf(p);
      }
    } else {
      for (int u=u0; u<u0+48; ++u) pb[t*104+u] = 0;
    }
    smv += __shfl_xor(smv,1);
    if (half==0) inv[t] = (t<LTK) ? 1.0f/smv : 0.0f;
  }
  __syncthreads();

  for (int rt = wid; rt < 6; rt += 4){
    int arow = rt*16 + (lane&15);
    f32x4 acc = (f32x4){0.f,0.f,0.f,0.f};
    #pragma unroll
    for (int ks=0; ks<3; ++ks){
      int kb = ks*32 + (lane>>4)*8;
      bf16x8 a  = *reinterpret_cast<const bf16x8*>(&pb[arow*104 + kb]);
      bf16x8 bf = *reinterpret_cast<const bf16x8*>(&vta[(lane&15)*108 + kb]);
      acc = __builtin_amdgcn_mfma_f32_16x16x32_bf16(a, bf, acc, 0,0,0);
    }
    #pragma unroll
    for (int rr=0; rr<4; ++rr){
      int rg = rt*16 + (lane>>4)*4 + rr;
      if (rg < LTK)
        y[(size_t)(b*LTK+rg)*128 + h*16 + (lane&15)] = f2bf(acc[rr]*inv[rg]);
    }
  }
}

// ==== fused FFN v4: 18-stage pipeline, explicit pairs, STATIC reg idx ======
template<bool HEAD>
__global__ __launch_bounds__(256, 2) void ffn_fused(
  const ushort_t* __restrict__ yg, const ushort_t* __restrict__ Wo,
  const float* __restrict__ bo, const float* __restrict__ g2,
  const float* __restrict__ b2g, const ushort_t* __restrict__ W1,
  const float* __restrict__ b1v, const ushort_t* __restrict__ W2,
  const float* __restrict__ b2v, float* __restrict__ x,
  const float* __restrict__ lnng, const float* __restrict__ lnnb,
  ushort_t* __restrict__ xlnout,
  const float* __restrict__ lnfg, const float* __restrict__ lnfb,
  const float* __restrict__ hw, float* __restrict__ out)
{
  __shared__ __align__(16) char sm[66304];
  ushort_t* wdb = (ushort_t*)sm;             // [2][64][128] swz  32768
  float*    xr  = (float*)(sm + 32768);      // [32][132] f32    16896
  ushort_t* h2  = (ushort_t*)(sm + 49664);   // [32][128] swz     8192
  ushort_t* f1  = (ushort_t*)(sm + 57856);   // [32][128] swz     8192 (=ys)
  const int tid = threadIdx.x, lane = tid & 63, wid = tid >> 6;
  const int m0 = blockIdx.x * 32;
  const int rr = tid >> 2, qq = tid & 3, swr = (rr&7)<<3;

  auto srcp = [&](int s)->const ushort_t* {
    if (s == 0) return Wo + (size_t)rr*128 + qq*32;
    if (s == 1) return Wo + (size_t)(64+rr)*128 + qq*32;
    int c = (s-2)>>2, r = (s-2)&3;
    if (r == 0) return W1 + (size_t)(c*128+rr)*128 + qq*32;
    if (r == 1) return W1 + (size_t)(c*128+64+rr)*128 + qq*32;
    if (r == 2) return W2 + (size_t)rr*512 + c*128 + qq*32;
    return W2 + (size_t)(64+rr)*512 + c*128 + qq*32;
  };
  auto issue = [&](us8 (&r)[4], int s){
    const ushort_t* p = srcp(s);
    #pragma unroll
    for (int g=0; g<4; ++g) r[g] = *reinterpret_cast<const us8*>(p + 8*g);
  };
  auto commit = [&](int buf, const us8 (&r)[4]){
    ushort_t* d = wdb + buf*8192 + rr*128;
    #pragma unroll
    for (int g=0; g<4; ++g)
      *reinterpret_cast<us8*>(&d[(qq*32+8*g) ^ swr]) = r[g];
  };
  auto gemmT = [&](const ushort_t* abuf, int buf, f32x4* accp){
    int nrow = wid*16 + (lane&15), nsw = (nrow&7)<<3;
    #pragma unroll
    for (int rt=0; rt<2; ++rt){
      int arow = rt*16 + (lane&15), asw = (arow&7)<<3;
      #pragma unroll
      for (int ks=0; ks<4; ++ks){
        int kb = ks*32 + (lane>>4)*8;
        bf16x8 a  = *reinterpret_cast<const bf16x8*>(&abuf[arow*128 + (kb ^ asw)]);
        bf16x8 bb = *reinterpret_cast<const bf16x8*>(&wdb[buf*8192 + nrow*128 + (kb ^ nsw)]);
        accp[rt] = __builtin_amdgcn_mfma_f32_16x16x32_bf16(a, bb, accp[rt], 0,0,0);
      }
    }
  };

  f32x4 accA[2][2], acc2[2][2];
  #pragma unroll
  for (int s_=0;s_<2;++s_){
    accA[s_][0]=(f32x4){0,0,0,0}; accA[s_][1]=(f32x4){0,0,0,0};
    acc2[s_][0]=(f32x4){0,0,0,0}; acc2[s_][1]=(f32x4){0,0,0,0};
  }

  auto computeStage = [&](int k, int buf){
    if (k == 0){
      gemmT(f1, buf, accA[0]);
    } else if (k == 1){
      gemmT(f1, buf, accA[1]);
      #pragma unroll
      for (int s_=0; s_<2; ++s_){
        int col = s_*64 + wid*16 + (lane&15);
        float bia = bo[col];
        #pragma unroll
        for (int rt=0; rt<2; ++rt)
          #pragma unroll
          for (int r4=0; r4<4; ++r4){
            int row = rt*16 + (lane>>4)*4 + r4;
            xr[row*132 + col] = accA[s_][rt][r4] + bia + x[(size_t)(m0+row)*128 + col];
          }
      }
      __syncthreads();
      { int r8 = tid>>3, q8 = tid&7;
        float xv[16];
        #pragma unroll
        for (int i=0;i<16;i++) xv[i] = xr[r8*132 + q8*16 + i];
        float s = 0;
        #pragma unroll
        for (int i=0;i<16;i++) s += xv[i];
        s += __shfl_xor(s,1); s += __shfl_xor(s,2); s += __shfl_xor(s,4);
        float mean = s * (1.0f/128.0f);
        float vs = 0;
        #pragma unroll
        for (int i=0;i<16;i++){ float d = xv[i]-mean; vs += d*d; }
        vs += __shfl_xor(vs,1); vs += __shfl_xor(vs,2); vs += __shfl_xor(vs,4);
        float rstd = rsqrtf(vs*(1.0f/128.0f) + 1e-5f);
        int sw = (r8&7)<<3;
        #pragma unroll
        for (int g=0; g<2; ++g){
          us8 o;
          #pragma unroll
          for (int jj=0;jj<8;jj++){
            int c = q8*16 + g*8 + jj;
            o[jj] = f2bf((xv[g*8+jj]-mean)*rstd*g2[c] + b2g[c]);
          }
          *reinterpret_cast<us8*>(&h2[r8*128 + ((q8*16+g*8) ^ sw)]) = o;
        }
      }
    } else {
      int r = (k-2)&3, c = (k-2)>>2;
      if (r < 2){
        f32x4 ac[2] = {(f32x4){0,0,0,0},(f32x4){0,0,0,0}};
        gemmT(h2, buf, ac);
        int cl = r*64 + wid*16 + (lane&15);
        float bia = b1v[c*128 + cl];
        #pragma unroll
        for (int rt=0; rt<2; ++rt)
          #pragma unroll
          for (int r4=0; r4<4; ++r4){
            int row = rt*16 + (lane>>4)*4 + r4;
            float v = ac[rt][r4] + bia;
            v = 0.5f*v*(1.0f + erff(v*0.70710678118654752f));
            f1[row*128 + (cl ^ ((row&7)<<3))] = f2bf(v);
          }
      } else if (r == 2){
        gemmT(f1, buf, acc2[0]);
      } else {
        gemmT(f1, buf, acc2[1]);
      }
    }
  };

  { int r8 = tid>>3, q8 = tid&7, sw = (r8&7)<<3;
    const ushort_t* src = yg + (size_t)(m0+r8)*128 + q8*16;
    *reinterpret_cast<us8*>(&f1[r8*128 + ((q8*16)   ^ sw)]) = *reinterpret_cast<const us8*>(src);
    *reinterpret_cast<us8*>(&f1[r8*128 + ((q8*16+8) ^ sw)]) = *reinterpret_cast<const us8*>(src+8);
  }
  us8 rA[4], rB[4];
  issue(rA, 0); issue(rB, 1);

  for (int kp = 0; kp < 9; ++kp){
    int k0 = 2*kp, k1 = 2*kp + 1;
    commit(0, rA);
    if (k0 + 2 < 18) issue(rA, k0 + 2);
    __syncthreads();
    computeStage(k0, 0);
    commit(1, rB);
    if (k1 + 2 < 18) issue(rB, k1 + 2);
    __syncthreads();
    computeStage(k1, 1);
  }

  #pragma unroll
  for (int s_=0; s_<2; ++s_){
    int col = s_*64 + wid*16 + (lane&15);
    float bia = b2v[col];
    #pragma unroll
    for (int rt=0; rt<2; ++rt)
      #pragma unroll
      for (int r4=0; r4<4; ++r4){
        int row = rt*16 + (lane>>4)*4 + r4;
        float v = acc2[s_][rt][r4] + bia + xr[row*132 + col];
        xr[row*132 + col] = v;
        if constexpr (!HEAD) x[(size_t)(m0+row)*128 + col] = v;
      }
  }
  __syncthreads();
  if constexpr (!HEAD){
    int r8 = tid>>3, q8 = tid&7;
    float xv[16];
    #pragma unroll
    for (int i=0;i<16;i++) xv[i] = xr[r8*132 + q8*16 + i];
    float s = 0;
    #pragma unroll
    for (int i=0;i<16;i++) s += xv[i];
    s += __shfl_xor(s,1); s += __shfl_xor(s,2); s += __shfl_xor(s,4);
    float mean = s * (1.0f/128.0f);
    float vs = 0;
    #pragma unroll
    for (int i=0;i<16;i++){ float d = xv[i]-mean; vs += d*d; }
    vs += __shfl_xor(vs,1); vs += __shfl_xor(vs,2); vs += __shfl_xor(vs,4);
    float rstd = rsqrtf(vs*(1.0f/128.0f) + 1e-5f);
    #pragma unroll
    for (int g=0; g<2; ++g){
      us8 o;
      #pragma unroll
      for (int jj=0;jj<8;jj++){
        int c = q8*16 + g*8 + jj;
        o[jj] = f2bf((xv[g*8+jj]-mean)*rstd*lnng[c] + lnnb[c]);
      }
      *reinterpret_cast<us8*>(xlnout + (size_t)(m0+r8)*128 + q8*16 + g*8) = o;
    }
  } else {
    for (int r = wid; r < 32; r += 4){
      int s = m0 + r, bb2 = s / LTK, p = s - bb2*LTK;
      if (p % 3 != 1) continue;
      int t = p / 3;
      float v1 = xr[r*132 + lane];
      float v2 = xr[r*132 + 64 + lane];
      float sum = v1 + v2;
      sum += __shfl_xor(sum,1); sum += __shfl_xor(sum,2); sum += __shfl_xor(sum,4);
      sum += __shfl_xor(sum,8); sum += __shfl_xor(sum,16); sum += __shfl_xor(sum,32);
      float mean = sum*(1.0f/128.0f);
      float d1 = v1-mean, d2 = v2-mean;
      float var = d1*d1 + d2*d2;
      var += __shfl_xor(var,1); var += __shfl_xor(var,2); var += __shfl_xor(var,4);
      var += __shfl_xor(var,8); var += __shfl_xor(var,16); var += __shfl_xor(var,32);
      float rstd = rsqrtf(var*(1.0f/128.0f) + 1e-5f);
      float h1 = d1*rstd*lnfg[lane]    + lnfb[lane];
      float h2v= d2*rstd*lnfg[lane+64] + lnfb[lane+64];
      #pragma unroll
      for (int o=0; o<NV; ++o){
        float sdot = h1*hw[o*128+lane] + h2v*hw[o*128+lane+64];
        sdot += __shfl_xor(sdot,1); sdot += __shfl_xor(sdot,2); sdot += __shfl_xor(sdot,4);
        sdot += __shfl_xor(sdot,8); sdot += __shfl_xor(sdot,16); sdot += __shfl_xor(sdot,32);
        if (lane == 0) out[(size_t)(bb2*NT+t)*NV + o] = sdot;
      }
    }
  }
}

// ===========================================================================
extern "C" void kernel_launch(void* const* d_in, const int* in_sizes, int n_in,
                              void* d_out, int out_size, void* d_ws, size_t ws_size,
                              hipStream_t stream)
{
  const float* states  = (const float*)d_in[0];
  const int*   actions = (const int*)  d_in[1];
  const float* rtgs    = (const float*)d_in[2];
  const int*   tsteps  = (const int*)  d_in[3];
  const float* conv_w  = (const float*)d_in[4];
  const float* ctok    = (const float*)d_in[5];
  const float* in_w    = (const float*)d_in[6];
  const float* in_b    = (const float*)d_in[7];
  const float* out_w   = (const float*)d_in[8];
  const float* out_b   = (const float*)d_in[9];
  const float* i1g     = (const float*)d_in[10];
  const float* i1b     = (const float*)d_in[11];
  const float* i2g     = (const float*)d_in[12];
  const float* i2b     = (const float*)d_in[13];
  const float* fw1     = (const float*)d_in[14];
  const float* fb1     = (const float*)d_in[15];
  const float* fw2     = (const float*)d_in[16];
  const float* fb2     = (const float*)d_in[17];
  const float* ret_w   = (const float*)d_in[18];
  const float* ret_b   = (const float*)d_in[19];
  const float* act_tab = (const float*)d_in[20];
  const float* pos_emb = (const float*)d_in[21];
  const float* gpos    = (const float*)d_in[22];
  const float* ln1g    = (const float*)d_in[23];
  const float* ln1b    = (const float*)d_in[24];
  const float* Wq      = (const float*)d_in[25];
  const float* bq      = (const float*)d_in[26];
  const float* Wk      = (const float*)d_in[27];
  const float* bk      = (const float*)d_in[28];
  const float* Wv      = (const float*)d_in[29];
  const float* bv      = (const float*)d_in[30];
  const float* Wo      = (const float*)d_in[31];
  const float* bo      = (const float*)d_in[32];
  const float* ln2g    = (const float*)d_in[33];
  const float* ln2b    = (const float*)d_in[34];
  const float* W1      = (const float*)d_in[35];
  const float* b1      = (const float*)d_in[36];
  const float* W2      = (const float*)d_in[37];
  const float* b2      = (const float*)d_in[38];
  const float* lnfg    = (const float*)d_in[39];
  const float* lnfb    = (const float*)d_in[40];
  const float* head_w  = (const float*)d_in[41];

  char* w = (char*)d_ws;
  size_t off = 0;
  auto alloc = [&](size_t bytes)->char* {
    char* p = w + off; off += (bytes + 255) & ~(size_t)255; return p;
  };
  float*    part  = (float*)   alloc((size_t)NZ*NBT*EE*4);
  float*    x     = (float*)   alloc((size_t)NS*EE*4);
  ushort_t* xlnA  = (ushort_t*)alloc((size_t)NS*EE*2);
  ushort_t* xlnB  = (ushort_t*)alloc((size_t)NS*EE*2);
  ushort_t* yb    = (ushort_t*)alloc((size_t)NS*EE*2);
  ushort_t* Wqkvb = (ushort_t*)alloc((size_t)NLY*384*128*2);
  ushort_t* Wob   = (ushort_t*)alloc((size_t)NLY*128*128*2);
  ushort_t* W1b   = (ushort_t*)alloc((size_t)NLY*512*128*2);
  ushort_t* W2b   = (ushort_t*)alloc((size_t)NLY*128*512*2);
  ushort_t* inwb  = (ushort_t*)alloc((size_t)384*128*2);
  ushort_t* outwb = (ushort_t*)alloc((size_t)128*128*2);
  ushort_t* f1wb  = (ushort_t*)alloc((size_t)128*128*2);
  ushort_t* f2wb  = (ushort_t*)alloc((size_t)128*128*2);
  float*    bqkv  = (float*)   alloc(NLY*384*4);
  (void)in_sizes; (void)n_in; (void)out_size; (void)ws_size;

  patch_conv<<<1881,256,0,stream>>>(states, conv_w, Wq,Wk,Wv,Wo,W1,W2,
                                    in_w,out_w,fw1,fw2, bq,bk,bv,
                                    Wqkvb,Wob,W1b,W2b, inwb,outwb,f1wb,f2wb,
                                    bqkv, part);
  inner_tit<<<240,256,0,stream>>>(part, ctok, inwb, in_b, outwb, out_b,
                                  i1g,i1b,i2g,i2b, f1wb,fb1, f2wb,fb2,
                                  rtgs, actions, tsteps, ret_w, ret_b, act_tab,
                                  pos_emb, gpos, ln1g, ln1b, x, xlnA);
  for (int i=0;i<NLY;i++){
    ushort_t* xin  = (i & 1) ? xlnB : xlnA;
    ushort_t* xout = (i & 1) ? xlnA : xlnB;
    attn_fused<<<512,256,0,stream>>>(
      xin, Wqkvb+(size_t)i*49152, bqkv+(size_t)i*384, yb);
    if (i < NLY-1)
      ffn_fused<false><<<178,256,0,stream>>>(
        yb, Wob+(size_t)i*16384, bo+i*128, ln2g+i*128, ln2b+i*128,
        W1b+(size_t)i*65536, b1+i*512, W2b+(size_t)i*65536, b2+i*128, x,
        ln1g+(i+1)*128, ln1b+(i+1)*128, xout,
        nullptr, nullptr, nullptr, nullptr);
    else
      ffn_fused<true><<<178,256,0,stream>>>(
        yb, Wob+(size_t)i*16384, bo+i*128, ln2g+i*128, ln2b+i*128,
        W1b+(size_t)i*65536, b1+i*512, W2b+(size_t)i*65536, b2+i*128, x,
        nullptr, nullptr, nullptr,
        lnfg, lnfb, head_w, (float*)d_out);
  }
}

// Round 14
// 315.270 us; speedup vs baseline: 1.1310x; 1.1310x over previous
//
#include <hip/hip_runtime.h>

#define NB   64
#define NT   30
#define NBT  1920        // NB*NT
#define EE   128
#define KP   28224       // 4*84*84
#define LTK  89          // 3*NT-1
#define NS   5696        // NB*LTK
#define NLY  6
#define NV   18
#define NZ   21          // split-K slabs for patch gemm

typedef unsigned short ushort_t;
using bf16x8 = __attribute__((ext_vector_type(8))) short;
using us8    = __attribute__((ext_vector_type(8))) unsigned short;
using f32x4  = __attribute__((ext_vector_type(4))) float;
using f32x16 = __attribute__((ext_vector_type(16))) float;

__device__ inline ushort_t f2bf(float f){
  union { float f; unsigned u; } v; v.f = f;
  unsigned r = v.u + 0x7FFFu + ((v.u >> 16) & 1u);   // RNE
  return (ushort_t)(r >> 16);
}
__device__ inline float bf2f(ushort_t h){
  union { unsigned u; float f; } v; v.u = ((unsigned)h) << 16; return v.f;
}

// ------- weights fp32->bf16 (incl. inner weights) + qkv bias pack ----------
__global__ __launch_bounds__(256) void wcvt(
  const float* conv, const float* Wq, const float* Wk, const float* Wv,
  const float* Wo, const float* W1, const float* W2,
  const float* in_w, const float* out_w, const float* f1w, const float* f2w,
  const float* bq, const float* bk, const float* bv,
  ushort_t* dc, ushort_t* dqkv, ushort_t* dout, ushort_t* d1, ushort_t* d2,
  ushort_t* dinw, ushort_t* doutw, ushort_t* df1, ushort_t* df2, float* bqkv)
{
  if (blockIdx.x >= 4776){                  // bias-pack tail
    int idx = (blockIdx.x-4776)*256 + threadIdx.x;
    if (idx < NLY*128){ int l=idx>>7, j=idx&127;
      bqkv[l*384+j]=bq[idx]; bqkv[l*384+128+j]=bk[idx]; bqkv[l*384+256+j]=bv[idx]; }
    return;
  }
  long i = 4l*((long)blockIdx.x*256 + threadIdx.x);
  if (i >= 3612672l && i < 3907584l){      // Wq | Wk | Wv  ->  (L,384,128)
    long o = i - 3612672l;
    int  seg = (int)(o / 98304l);
    long off2 = o - (long)seg*98304l;
    long layer = off2 >> 14, rem = off2 & 16383l;
    const float* s = (seg==0) ? Wq : (seg==1) ? Wk : Wv;
    float4 f = *reinterpret_cast<const float4*>(s+off2);
    long dst = layer*49152l + (long)seg*16384l + rem;
    dqkv[dst]=f2bf(f.x); dqkv[dst+1]=f2bf(f.y); dqkv[dst+2]=f2bf(f.z); dqkv[dst+3]=f2bf(f.w);
    return;
  }
  const float* s; ushort_t* d; long off;
  if      (i < 3612672l){ s=conv;  d=dc;    off=i; }
  else if (i < 4005888l){ s=Wo;    d=dout;  off=i-3907584l; }
  else if (i < 4399104l){ s=W1;    d=d1;    off=i-4005888l; }
  else if (i < 4792320l){ s=W2;    d=d2;    off=i-4399104l; }
  else if (i < 4841472l){ s=in_w;  d=dinw;  off=i-4792320l; }
  else if (i < 4857856l){ s=out_w; d=doutw; off=i-4841472l; }
  else if (i < 4874240l){ s=f1w;   d=df1;   off=i-4857856l; }
  else                  { s=f2w;   d=df2;   off=i-4874240l; }
  float4 f = *reinterpret_cast<const float4*>(s+off);
  d[off]=f2bf(f.x); d[off+1]=f2bf(f.y); d[off+2]=f2bf(f.z); d[off+3]=f2bf(f.w);
}

// ---- patch embed v4: LDS dbuf + 2-deep prefetch, STATIC reg indexing ------
__global__ __launch_bounds__(256) void patch_gemm(
  const float* __restrict__ A, const ushort_t* __restrict__ Wb, float* __restrict__ C)
{
  __shared__ __align__(16) ushort_t As[2][64*64];
  __shared__ __align__(16) ushort_t Ws[2][128*64];
  const int tid = threadIdx.x, lane = tid & 63, wid = tid >> 6;
  const int m0 = blockIdx.x * 64;
  const int kbase = blockIdx.z * 1344;
  float* Cz = C + (size_t)blockIdx.z * NBT * EE;
  const int ra = tid>>2, ca = (tid&3)*16, swa = (ra&7)<<3;
  const int rw = tid>>1, cw = (tid&1)*32, sww = (rw&7)<<3;
  const float*    Ab = A  + (size_t)(m0+ra)*KP + kbase + ca;
  const ushort_t* Wp = Wb + (size_t)rw*KP  + kbase + cw;
  f32x4 acc[8];
  #pragma unroll
  for (int j=0;j<8;j++) acc[j] = (f32x4){0.f,0.f,0.f,0.f};

  auto loadT = [&](float4 (&fa)[4], us8 (&wr)[4], int kt){
    #pragma unroll
    for (int q=0;q<4;q++){
      fa[q] = *reinterpret_cast<const float4*>(Ab + kt*64 + 4*q);
      wr[q] = *reinterpret_cast<const us8*>(Wp + kt*64 + 8*q);
    }
  };
  auto commitT = [&](int buf, const float4 (&fa)[4], const us8 (&wr)[4]){
    us8 o0, o1;
    o0[0]=f2bf(fa[0].x); o0[1]=f2bf(fa[0].y); o0[2]=f2bf(fa[0].z); o0[3]=f2bf(fa[0].w);
    o0[4]=f2bf(fa[1].x); o0[5]=f2bf(fa[1].y); o0[6]=f2bf(fa[1].z); o0[7]=f2bf(fa[1].w);
    o1[0]=f2bf(fa[2].x); o1[1]=f2bf(fa[2].y); o1[2]=f2bf(fa[2].z); o1[3]=f2bf(fa[2].w);
    o1[4]=f2bf(fa[3].x); o1[5]=f2bf(fa[3].y); o1[6]=f2bf(fa[3].z); o1[7]=f2bf(fa[3].w);
    *reinterpret_cast<us8*>(&As[buf][ra*64 + ( ca    ^ swa)]) = o0;
    *reinterpret_cast<us8*>(&As[buf][ra*64 + ((ca+8) ^ swa)]) = o1;
    #pragma unroll
    for (int q=0;q<4;q++)
      *reinterpret_cast<us8*>(&Ws[buf][rw*64 + ((cw+8*q) ^ sww)]) = wr[q];
  };
  auto computeT = [&](int buf){
    #pragma unroll
    for (int ks=0; ks<2; ++ks){
      int arow = wid*16 + (lane&15);
      int kb = ks*32 + (lane>>4)*8;
      bf16x8 a = *reinterpret_cast<const bf16x8*>(&As[buf][arow*64 + (kb ^ ((arow&7)<<3))]);
      #pragma unroll
      for (int nt=0; nt<8; ++nt){
        int nn = nt*16 + (lane&15);
        bf16x8 b = *reinterpret_cast<const bf16x8*>(&Ws[buf][nn*64 + (kb ^ ((nn&7)<<3))]);
        acc[nt] = __builtin_amdgcn_mfma_f32_16x16x32_bf16(a, b, acc[nt], 0,0,0);
      }
    }
  };

  float4 faA[4], faB[4]; us8 wrA[4], wrB[4];
  loadT(faA, wrA, 0);
  loadT(faB, wrB, 1);
  for (int kp = 0; kp < 11; ++kp){
    int kt0 = 2*kp;
    commitT(0, faA, wrA);
    if (kt0 + 2 < 21) loadT(faA, wrA, kt0 + 2);
    __syncthreads();
    computeT(0);
    int kt1 = kt0 + 1;
    if (kt1 < 21){
      commitT(1, faB, wrB);
      if (kt1 + 2 < 21) loadT(faB, wrB, kt1 + 2);
      __syncthreads();
      computeT(1);
    }
  }
  #pragma unroll
  for (int nt=0; nt<8; ++nt)
    #pragma unroll
    for (int rr=0;rr<4;rr++){
      int row = m0 + wid*16 + (lane>>4)*4 + rr;
      int col = nt*16 + (lane&15);
      Cz[row*EE + col] = acc[nt][rr];
    }
}

// ======= inner TIT v2: 8 bt per block, MFMA, staged bf16 weights ===========
__global__ __launch_bounds__(256, 1) void inner_tit(
  const float* __restrict__ part, const float* __restrict__ ctok,
  const ushort_t* __restrict__ inw, const float* __restrict__ in_b,
  const ushort_t* __restrict__ outw, const float* __restrict__ out_b,
  const float* __restrict__ g1, const float* __restrict__ b1_,
  const float* __restrict__ g2, const float* __restrict__ b2_,
  const ushort_t* __restrict__ f1wb, const float* __restrict__ fb1,
  const ushort_t* __restrict__ f2wb, const float* __restrict__ fb2,
  const float* __restrict__ rtgs, const int* __restrict__ actions,
  const int* __restrict__ tsteps, const float* __restrict__ ret_w,
  const float* __restrict__ ret_b, const float* __restrict__ act_tab,
  const float* __restrict__ pos_emb, const float* __restrict__ gpos,
  const float* __restrict__ ln1g0, const float* __restrict__ ln1b0,
  float* __restrict__ x, ushort_t* __restrict__ xln)
{
  __shared__ __align__(16) ushort_t wbuf[384*128];
  __shared__ float xs[16*128];
  __shared__ __align__(16) ushort_t hb[16*128];
  __shared__ __align__(16) ushort_t hf[16*128];
  __shared__ float qkv[16*384];
  __shared__ float ssm[32];
  const int tid = threadIdx.x, lane = tid & 63, wid = tid >> 6;
  const int bt0 = blockIdx.x * 8;

  auto stageWB = [&](const ushort_t* src, int R, int rowoff){
    for (int c = tid; c < R*16; c += 256){
      int rr = c >> 4, cc = (c & 15) * 8;
      *reinterpret_cast<us8*>(&wbuf[(rowoff+rr)*128 + (cc ^ ((rr&7)<<3))]) =
        *reinterpret_cast<const us8*>(src + (size_t)rr*128 + cc);
    }
  };
  auto lnrow = [&](const float* gam, const float* bet, ushort_t* dst){
    int r = tid >> 4, e0 = (tid & 15) * 8;
    float v[8];
    #pragma unroll
    for (int j=0;j<8;j++) v[j] = xs[r*128 + e0 + j];
    float s = 0;
    #pragma unroll
    for (int j=0;j<8;j++) s += v[j];
    s += __shfl_xor(s,1); s += __shfl_xor(s,2); s += __shfl_xor(s,4); s += __shfl_xor(s,8);
    float mean = s * (1.0f/128.0f);
    float vs = 0;
    #pragma unroll
    for (int j=0;j<8;j++){ float d = v[j]-mean; vs += d*d; }
    vs += __shfl_xor(vs,1); vs += __shfl_xor(vs,2); vs += __shfl_xor(vs,4); vs += __shfl_xor(vs,8);
    float rstd = rsqrtf(vs*(1.0f/128.0f) + 1e-5f);
    us8 o;
    #pragma unroll
    for (int j=0;j<8;j++) o[j] = f2bf((v[j]-mean)*rstd*gam[e0+j] + bet[e0+j]);
    *reinterpret_cast<us8*>(&dst[r*128 + (e0 ^ ((r&7)<<3))]) = o;
  };

  { int r = tid >> 4, e0 = (tid & 15) * 8;
    float v[8];
    if ((r & 1) == 0){
      #pragma unroll
      for (int j=0;j<8;j++) v[j] = ctok[e0+j];
    } else {
      #pragma unroll
      for (int j=0;j<8;j++) v[j] = 0.f;
      int bt = bt0 + (r>>1);
      for (int z=0; z<NZ; ++z){
        const float* p = part + (size_t)z*NBT*EE + (size_t)bt*128 + e0;
        float4 f0 = *reinterpret_cast<const float4*>(p);
        float4 f1 = *reinterpret_cast<const float4*>(p+4);
        v[0]+=f0.x; v[1]+=f0.y; v[2]+=f0.z; v[3]+=f0.w;
        v[4]+=f1.x; v[5]+=f1.y; v[6]+=f1.z; v[7]+=f1.w;
      }
    }
    #pragma unroll
    for (int j=0;j<8;j++) xs[r*128 + e0 + j] = v[j];
  }
  stageWB(inw, 384, 0);
  __syncthreads();

  lnrow(g1, b1_, hb);
  __syncthreads();

  { int al = lane & 15, kq = (lane>>4)*8;
    #pragma unroll
    for (int j=0;j<6;++j){
      int nt = wid*6 + j;
      f32x4 acc = (f32x4){0.f,0.f,0.f,0.f};
      int nrow = nt*16 + al, nsw = (nrow&7)<<3;
      #pragma unroll
      for (int ks=0; ks<4; ++ks){
        int kb = ks*32 + kq;
        bf16x8 a = *reinterpret_cast<const bf16x8*>(&hb[al*128 + (kb ^ ((al&7)<<3))]);
        bf16x8 b = *reinterpret_cast<const bf16x8*>(&wbuf[nrow*128 + (kb ^ nsw)]);
        acc = __builtin_amdgcn_mfma_f32_16x16x32_bf16(a, b, acc, 0,0,0);
      }
      float bia = in_b[nt*16 + al];
      #pragma unroll
      for (int rr=0; rr<4; ++rr){
        int row = (lane>>4)*4 + rr;
        qkv[row*384 + nt*16 + al] = acc[rr] + bia;
      }
    }
  }
  __syncthreads();

  { int d = tid >> 3, j = tid & 7;
    int i = d >> 2, p = d & 3;
    const float* qp = &qkv[(2*i + (p>>1))*384 + j*16];
    const float* kp = &qkv[(2*i + (p&1))*384 + 128 + j*16];
    float s = 0;
    #pragma unroll
    for (int e=0;e<16;e++) s += qp[e]*kp[e];
    s += __shfl_xor(s,1); s += __shfl_xor(s,2); s += __shfl_xor(s,4);
    if (j == 0) ssm[d] = s;
  }
  stageWB(outw, 128, 0);
  stageWB(f1wb, 128, 128);
  stageWB(f2wb, 128, 256);
  __syncthreads();

  { int r = tid >> 4, e0 = (tid & 15)*8;
    int i = r >> 1, t = r & 1;
    const float sc = 0.08838834764831845f;
    float s0 = ssm[i*4 + t*2]*sc, s1 = ssm[i*4 + t*2 + 1]*sc;
    float m = fmaxf(s0,s1), p0 = __expf(s0-m), p1 = __expf(s1-m);
    float iv = 1.0f/(p0+p1); p0 *= iv; p1 *= iv;
    const float* v0 = &qkv[(2*i)*384 + 256 + e0];
    const float* v1 = &qkv[(2*i+1)*384 + 256 + e0];
    us8 o;
    #pragma unroll
    for (int j=0;j<8;j++) o[j] = f2bf(p0*v0[j] + p1*v1[j]);
    *reinterpret_cast<us8*>(&hb[r*128 + (e0 ^ ((r&7)<<3))]) = o;
  }
  __syncthreads();

  { int al = lane & 15, kq = (lane>>4)*8;
    #pragma unroll
    for (int j=0;j<2;++j){
      int nt = wid*2 + j;
      f32x4 acc = (f32x4){0.f,0.f,0.f,0.f};
      int nrow = nt*16 + al, nsw = (nrow&7)<<3;
      #pragma unroll
      for (int ks=0; ks<4; ++ks){
        int kb = ks*32 + kq;
        bf16x8 a = *reinterpret_cast<const bf16x8*>(&hb[al*128 + (kb ^ ((al&7)<<3))]);
        bf16x8 b = *reinterpret_cast<const bf16x8*>(&wbuf[nrow*128 + (kb ^ nsw)]);
        acc = __builtin_amdgcn_mfma_f32_16x16x32_bf16(a, b, acc, 0,0,0);
      }
      float bia = out_b[nt*16 + al];
      #pragma unroll
      for (int rr=0; rr<4; ++rr){
        int row = (lane>>4)*4 + rr;
        xs[row*128 + nt*16 + al] += acc[rr] + bia;
      }
    }
  }
  __syncthreads();

  lnrow(g2, b2_, hb);
  __syncthreads();

  { int al = lane & 15, kq = (lane>>4)*8;
    #pragma unroll
    for (int j=0;j<2;++j){
      int nt = wid*2 + j;
      f32x4 acc = (f32x4){0.f,0.f,0.f,0.f};
      int nrow = nt*16 + al, nsw = (nrow&7)<<3;
      #pragma unroll
      for (int ks=0; ks<4; ++ks){
        int kb = ks*32 + kq;
        bf16x8 a = *reinterpret_cast<const bf16x8*>(&hb[al*128 + (kb ^ ((al&7)<<3))]);
        bf16x8 b = *reinterpret_cast<const bf16x8*>(&wbuf[(128+nrow)*128 + (kb ^ nsw)]);
        acc = __builtin_amdgcn_mfma_f32_16x16x32_bf16(a, b, acc, 0,0,0);
      }
      float bia = fb1[nt*16 + al];
      #pragma unroll
      for (int rr=0; rr<4; ++rr){
        int row = (lane>>4)*4 + rr;
        hf[row*128 + ((nt*16+al) ^ ((row&7)<<3))] = f2bf(fmaxf(acc[rr] + bia, 0.f));
      }
    }
  }
  __syncthreads();

  { int al = lane & 15, kq = (lane>>4)*8;
    #pragma unroll
    for (int j=0;j<2;++j){
      int nt = wid*2 + j;
      f32x4 acc = (f32x4){0.f,0.f,0.f,0.f};
      int nrow = nt*16 + al, nsw = (nrow&7)<<3;
      #pragma unroll
      for (int ks=0; ks<4; ++ks){
        int kb = ks*32 + kq;
        bf16x8 a = *reinterpret_cast<const bf16x8*>(&hf[al*128 + (kb ^ ((al&7)<<3))]);
        bf16x8 b = *reinterpret_cast<const bf16x8*>(&wbuf[(256+nrow)*128 + (kb ^ nsw)]);
        acc = __builtin_amdgcn_mfma_f32_16x16x32_bf16(a, b, acc, 0,0,0);
      }
      float bia = fb2[nt*16 + al];
      #pragma unroll
      for (int rr=0; rr<4; ++rr){
        int row = (lane>>4)*4 + rr;
        xs[row*128 + nt*16 + al] += acc[rr] + bia;
      }
    }
  }
  __syncthreads();

  { int q = tid >> 3, j = tid & 7;
    if (q < 24){
      int i = q / 3, kind = q - 3*i;
      int btg = bt0 + i, b = btg / NT, t = btg - b*NT;
      bool valid = !(kind == 2 && t == 0);
      if (valid){
        int prow = (kind==0) ? 3*t : (kind==1) ? 3*t+1 : 3*t-1;
        size_t xrow = ((size_t)b*LTK + prow)*128;
        int ts = tsteps[b];
        int e0 = j*16;
        float v[16];
        if (kind == 1){
          #pragma unroll
          for (int e=0;e<16;e++) v[e] = xs[(2*i)*128 + e0 + e];
        } else if (kind == 0){
          float rv = rtgs[b*NT+t];
          #pragma unroll
          for (int e=0;e<16;e++) v[e] = tanhf(rv*ret_w[e0+e] + ret_b[e0+e]);
        } else {
          int a = actions[b*NT+t];
          #pragma unroll
          for (int e=0;e<16;e++) v[e] = tanhf(act_tab[a*128 + e0 + e]);
        }
        #pragma unroll
        for (int e=0;e<16;e++)
          v[e] += gpos[(size_t)ts*128 + e0 + e] + pos_emb[prow*128 + e0 + e];
        #pragma unroll
        for (int e=0;e<16;e++) x[xrow + e0 + e] = v[e];
        float s = 0;
        #pragma unroll
        for (int e=0;e<16;e++) s += v[e];
        s += __shfl_xor(s,1); s += __shfl_xor(s,2); s += __shfl_xor(s,4);
        float mean = s * (1.0f/128.0f);
        float vs = 0;
        #pragma unroll
        for (int e=0;e<16;e++){ float d = v[e]-mean; vs += d*d; }
        vs += __shfl_xor(vs,1); vs += __shfl_xor(vs,2); vs += __shfl_xor(vs,4);
        float rstd = rsqrtf(vs*(1.0f/128.0f) + 1e-5f);
        #pragma unroll
        for (int e=0;e<16;e++)
          xln[xrow + e0 + e] = f2bf((v[e]-mean)*rstd*ln1g0[e0+e] + ln1b0[e0+e]);
      }
    }
  }
}

// ======== fused attention: one block per (b,h); reads pre-LN'd xln =========
__global__ __launch_bounds__(256, 2) void attn_fused(
  const ushort_t* __restrict__ xln, const ushort_t* __restrict__ Wqkv,
  const float* __restrict__ bqkv, ushort_t* __restrict__ y)
{
  __shared__ __align__(16) char sm[69504];
  ushort_t* ab  = (ushort_t*)sm;              // [96][128] bf16 swz (24576)
  ushort_t* wb  = (ushort_t*)(sm + 24576);    // [48][128] bf16 swz (12288)
  float*    S   = (float*)sm;                 // [96][97] f32 union ab/wb
  ushort_t* qa  = (ushort_t*)(sm + 37248);    // [96][22] bf16
  ushort_t* ka  = (ushort_t*)(sm + 41472);    // [96][22]
  ushort_t* vta = (ushort_t*)(sm + 45696);    // [16][108] V^T
  ushort_t* pb  = (ushort_t*)(sm + 49152);    // [96][104]
  float*    inv = (float*)(sm + 69120);       // [96]

  const int b = blockIdx.x >> 3, h = blockIdx.x & 7;
  const int tid = threadIdx.x, lane = tid & 63, wid = tid >> 6;

  for (int idx = tid; idx < 1536; idx += 256){
    int row = idx >> 4, c0 = (idx & 15) * 8;
    us8 v;
    if (row < LTK) v = *reinterpret_cast<const us8*>(xln + ((size_t)(b*LTK+row))*128 + c0);
    else           v = (us8){0,0,0,0,0,0,0,0};
    *reinterpret_cast<us8*>(&ab[row*128 + (c0 ^ ((row&7)<<3))]) = v;
  }
  for (int idx = tid; idx < 384; idx += 256){
    int rr = idx >> 3, c = (idx & 7) * 16;
    int seg = rr >> 4, n = rr & 15;
    const ushort_t* src = Wqkv + (size_t)(seg*128 + h*16 + n)*128 + c;
    int sw = (rr&7)<<3;
    *reinterpret_cast<us8*>(&wb[rr*128 + ( c    ^ sw)]) = *reinterpret_cast<const us8*>(src);
    *reinterpret_cast<us8*>(&wb[rr*128 + ((c+8) ^ sw)]) = *reinterpret_cast<const us8*>(src+8);
  }
  __syncthreads();

  for (int idx = wid; idx < 18; idx += 4){
    int rt = idx / 3, nt = idx - 3*(idx/3);
    f32x4 acc = (f32x4){0.f,0.f,0.f,0.f};
    int arow = rt*16 + (lane&15), asw = (arow&7)<<3;
    int nrow = nt*16 + (lane&15), nsw = (nrow&7)<<3;
    #pragma unroll
    for (int ks=0; ks<4; ++ks){
      int kb = ks*32 + (lane>>4)*8;
      bf16x8 a = *reinterpret_cast<const bf16x8*>(&ab[arow*128 + (kb ^ asw)]);
      bf16x8 bf = *reinterpret_cast<const bf16x8*>(&wb[nrow*128 + (kb ^ nsw)]);
      acc = __builtin_amdgcn_mfma_f32_16x16x32_bf16(a, bf, acc, 0,0,0);
    }
    int d = lane & 15;
    float bia = bqkv[nt*128 + h*16 + d];
    #pragma unroll
    for (int rr=0; rr<4; ++rr){
      int rg = rt*16 + (lane>>4)*4 + rr;
      ushort_t hv = f2bf(acc[rr] + bia);
      if      (nt == 0) qa[rg*22 + d] = hv;
      else if (nt == 1) ka[rg*22 + d] = hv;
      else              vta[d*108 + rg] = hv;
    }
  }
  __syncthreads();

  {
    static const int TR[6] = {0,1,1,2,2,2};
    static const int TC[6] = {0,0,1,0,1,2};
    for (int idx = wid; idx < 6; idx += 4){
      int R = TR[idx], C = TC[idx];
      int arow = R*32 + (lane&31), brow = C*32 + (lane&31);
      int ke = (lane>>5)*8;
      bf16x8 a  = *reinterpret_cast<const bf16x8*>(&qa[arow*22 + ke]);
      bf16x8 bf = *reinterpret_cast<const bf16x8*>(&ka[brow*22 + ke]);
      f32x16 sc = {};
      sc = __builtin_amdgcn_mfma_f32_32x32x16_bf16(a, bf, sc, 0,0,0);
      #pragma unroll
      for (int r=0; r<16; ++r){
        int rin = (r&3) + 8*(r>>2) + 4*(lane>>5);
        S[(R*32+rin)*97 + C*32 + (lane&31)] = sc[r]*0.25f;
      }
    }
  }
  __syncthreads();

  if (tid < 192){
    int t = tid >> 1, half = tid & 1;
    int u0 = half*48;
    float mx = -1e30f;
    if (t < LTK){
      for (int u=u0; u<u0+48; ++u) if (u<=t) mx = fmaxf(mx, S[t*97+u]);
    }
    mx = fmaxf(mx, __shfl_xor(mx,1));
    float smv = 0;
    if (t < LTK){
      for (int u=u0; u<u0+48; ++u){
        float p = 0;
        if (u<=t){ p = __expf(S[t*97+u]-mx); smv += p; }
        pb[t*104+u] = f2bf(p);
      }
    } else {
      for (int u=u0; u<u0+48; ++u) pb[t*104+u] = 0;
    }
    smv += __shfl_xor(smv,1);
    if (half==0) inv[t] = (t<LTK) ? 1.0f/smv : 0.0f;
  }
  __syncthreads();

  for (int rt = wid; rt < 6; rt += 4){
    int arow = rt*16 + (lane&15);
    f32x4 acc = (f32x4){0.f,0.f,0.f,0.f};
    #pragma unroll
    for (int ks=0; ks<3; ++ks){
      int kb = ks*32 + (lane>>4)*8;
      bf16x8 a  = *reinterpret_cast<const bf16x8*>(&pb[arow*104 + kb]);
      bf16x8 bf = *reinterpret_cast<const bf16x8*>(&vta[(lane&15)*108 + kb]);
      acc = __builtin_amdgcn_mfma_f32_16x16x32_bf16(a, bf, acc, 0,0,0);
    }
    #pragma unroll
    for (int rr=0; rr<4; ++rr){
      int rg = rt*16 + (lane>>4)*4 + rr;
      if (rg < LTK)
        y[(size_t)(b*LTK+rg)*128 + h*16 + (lane&15)] = f2bf(acc[rr]*inv[rg]);
    }
  }
}

// ==== fused FFN v4: 18-stage pipeline, explicit pairs, STATIC reg idx ======
template<bool HEAD>
__global__ __launch_bounds__(256, 2) void ffn_fused(
  const ushort_t* __restrict__ yg, const ushort_t* __restrict__ Wo,
  const float* __restrict__ bo, const float* __restrict__ g2,
  const float* __restrict__ b2g, const ushort_t* __restrict__ W1,
  const float* __restrict__ b1v, const ushort_t* __restrict__ W2,
  const float* __restrict__ b2v, float* __restrict__ x,
  const float* __restrict__ lnng, const float* __restrict__ lnnb,
  ushort_t* __restrict__ xlnout,
  const float* __restrict__ lnfg, const float* __restrict__ lnfb,
  const float* __restrict__ hw, float* __restrict__ out)
{
  __shared__ __align__(16) char sm[66304];
  ushort_t* wdb = (ushort_t*)sm;             // [2][64][128] swz  32768
  float*    xr  = (float*)(sm + 32768);      // [32][132] f32    16896
  ushort_t* h2  = (ushort_t*)(sm + 49664);   // [32][128] swz     8192
  ushort_t* f1  = (ushort_t*)(sm + 57856);   // [32][128] swz     8192 (=ys)
  const int tid = threadIdx.x, lane = tid & 63, wid = tid >> 6;
  const int m0 = blockIdx.x * 32;
  const int rr = tid >> 2, qq = tid & 3, swr = (rr&7)<<3;

  auto srcp = [&](int s)->const ushort_t* {
    if (s == 0) return Wo + (size_t)rr*128 + qq*32;
    if (s == 1) return Wo + (size_t)(64+rr)*128 + qq*32;
    int c = (s-2)>>2, r = (s-2)&3;
    if (r == 0) return W1 + (size_t)(c*128+rr)*128 + qq*32;
    if (r == 1) return W1 + (size_t)(c*128+64+rr)*128 + qq*32;
    if (r == 2) return W2 + (size_t)rr*512 + c*128 + qq*32;
    return W2 + (size_t)(64+rr)*512 + c*128 + qq*32;
  };
  auto issue = [&](us8 (&r)[4], int s){
    const ushort_t* p = srcp(s);
    #pragma unroll
    for (int g=0; g<4; ++g) r[g] = *reinterpret_cast<const us8*>(p + 8*g);
  };
  auto commit = [&](int buf, const us8 (&r)[4]){
    ushort_t* d = wdb + buf*8192 + rr*128;
    #pragma unroll
    for (int g=0; g<4; ++g)
      *reinterpret_cast<us8*>(&d[(qq*32+8*g) ^ swr]) = r[g];
  };
  auto gemmT = [&](const ushort_t* abuf, int buf, f32x4* accp){
    int nrow = wid*16 + (lane&15), nsw = (nrow&7)<<3;
    #pragma unroll
    for (int rt=0; rt<2; ++rt){
      int arow = rt*16 + (lane&15), asw = (arow&7)<<3;
      #pragma unroll
      for (int ks=0; ks<4; ++ks){
        int kb = ks*32 + (lane>>4)*8;
        bf16x8 a  = *reinterpret_cast<const bf16x8*>(&abuf[arow*128 + (kb ^ asw)]);
        bf16x8 bb = *reinterpret_cast<const bf16x8*>(&wdb[buf*8192 + nrow*128 + (kb ^ nsw)]);
        accp[rt] = __builtin_amdgcn_mfma_f32_16x16x32_bf16(a, bb, accp[rt], 0,0,0);
      }
    }
  };

  f32x4 accA[2][2], acc2[2][2];
  #pragma unroll
  for (int s_=0;s_<2;++s_){
    accA[s_][0]=(f32x4){0,0,0,0}; accA[s_][1]=(f32x4){0,0,0,0};
    acc2[s_][0]=(f32x4){0,0,0,0}; acc2[s_][1]=(f32x4){0,0,0,0};
  }

  auto computeStage = [&](int k, int buf){
    if (k == 0){
      gemmT(f1, buf, accA[0]);
    } else if (k == 1){
      gemmT(f1, buf, accA[1]);
      #pragma unroll
      for (int s_=0; s_<2; ++s_){
        int col = s_*64 + wid*16 + (lane&15);
        float bia = bo[col];
        #pragma unroll
        for (int rt=0; rt<2; ++rt)
          #pragma unroll
          for (int r4=0; r4<4; ++r4){
            int row = rt*16 + (lane>>4)*4 + r4;
            xr[row*132 + col] = accA[s_][rt][r4] + bia + x[(size_t)(m0+row)*128 + col];
          }
      }
      __syncthreads();
      { int r8 = tid>>3, q8 = tid&7;
        float xv[16];
        #pragma unroll
        for (int i=0;i<16;i++) xv[i] = xr[r8*132 + q8*16 + i];
        float s = 0;
        #pragma unroll
        for (int i=0;i<16;i++) s += xv[i];
        s += __shfl_xor(s,1); s += __shfl_xor(s,2); s += __shfl_xor(s,4);
        float mean = s * (1.0f/128.0f);
        float vs = 0;
        #pragma unroll
        for (int i=0;i<16;i++){ float d = xv[i]-mean; vs += d*d; }
        vs += __shfl_xor(vs,1); vs += __shfl_xor(vs,2); vs += __shfl_xor(vs,4);
        float rstd = rsqrtf(vs*(1.0f/128.0f) + 1e-5f);
        int sw = (r8&7)<<3;
        #pragma unroll
        for (int g=0; g<2; ++g){
          us8 o;
          #pragma unroll
          for (int jj=0;jj<8;jj++){
            int c = q8*16 + g*8 + jj;
            o[jj] = f2bf((xv[g*8+jj]-mean)*rstd*g2[c] + b2g[c]);
          }
          *reinterpret_cast<us8*>(&h2[r8*128 + ((q8*16+g*8) ^ sw)]) = o;
        }
      }
    } else {
      int r = (k-2)&3, c = (k-2)>>2;
      if (r < 2){
        f32x4 ac[2] = {(f32x4){0,0,0,0},(f32x4){0,0,0,0}};
        gemmT(h2, buf, ac);
        int cl = r*64 + wid*16 + (lane&15);
        float bia = b1v[c*128 + cl];
        #pragma unroll
        for (int rt=0; rt<2; ++rt)
          #pragma unroll
          for (int r4=0; r4<4; ++r4){
            int row = rt*16 + (lane>>4)*4 + r4;
            float v = ac[rt][r4] + bia;
            v = 0.5f*v*(1.0f + erff(v*0.70710678118654752f));
            f1[row*128 + (cl ^ ((row&7)<<3))] = f2bf(v);
          }
      } else if (r == 2){
        gemmT(f1, buf, acc2[0]);
      } else {
        gemmT(f1, buf, acc2[1]);
      }
    }
  };

  { int r8 = tid>>3, q8 = tid&7, sw = (r8&7)<<3;
    const ushort_t* src = yg + (size_t)(m0+r8)*128 + q8*16;
    *reinterpret_cast<us8*>(&f1[r8*128 + ((q8*16)   ^ sw)]) = *reinterpret_cast<const us8*>(src);
    *reinterpret_cast<us8*>(&f1[r8*128 + ((q8*16+8) ^ sw)]) = *reinterpret_cast<const us8*>(src+8);
  }
  us8 rA[4], rB[4];
  issue(rA, 0); issue(rB, 1);

  for (int kp = 0; kp < 9; ++kp){
    int k0 = 2*kp, k1 = 2*kp + 1;
    commit(0, rA);
    if (k0 + 2 < 18) issue(rA, k0 + 2);
    __syncthreads();
    computeStage(k0, 0);
    commit(1, rB);
    if (k1 + 2 < 18) issue(rB, k1 + 2);
    __syncthreads();
    computeStage(k1, 1);
  }

  #pragma unroll
  for (int s_=0; s_<2; ++s_){
    int col = s_*64 + wid*16 + (lane&15);
    float bia = b2v[col];
    #pragma unroll
    for (int rt=0; rt<2; ++rt)
      #pragma unroll
      for (int r4=0; r4<4; ++r4){
        int row = rt*16 + (lane>>4)*4 + r4;
        float v = acc2[s_][rt][r4] + bia + xr[row*132 + col];
        xr[row*132 + col] = v;
        if constexpr (!HEAD) x[(size_t)(m0+row)*128 + col] = v;
      }
  }
  __syncthreads();
  if constexpr (!HEAD){
    int r8 = tid>>3, q8 = tid&7;
    float xv[16];
    #pragma unroll
    for (int i=0;i<16;i++) xv[i] = xr[r8*132 + q8*16 + i];
    float s = 0;
    #pragma unroll
    for (int i=0;i<16;i++) s += xv[i];
    s += __shfl_xor(s,1); s += __shfl_xor(s,2); s += __shfl_xor(s,4);
    float mean = s * (1.0f/128.0f);
    float vs = 0;
    #pragma unroll
    for (int i=0;i<16;i++){ float d = xv[i]-mean; vs += d*d; }
    vs += __shfl_xor(vs,1); vs += __shfl_xor(vs,2); vs += __shfl_xor(vs,4);
    float rstd = rsqrtf(vs*(1.0f/128.0f) + 1e-5f);
    #pragma unroll
    for (int g=0; g<2; ++g){
      us8 o;
      #pragma unroll
      for (int jj=0;jj<8;jj++){
        int c = q8*16 + g*8 + jj;
        o[jj] = f2bf((xv[g*8+jj]-mean)*rstd*lnng[c] + lnnb[c]);
      }
      *reinterpret_cast<us8*>(xlnout + (size_t)(m0+r8)*128 + q8*16 + g*8) = o;
    }
  } else {
    for (int r = wid; r < 32; r += 4){
      int s = m0 + r, bb2 = s / LTK, p = s - bb2*LTK;
      if (p % 3 != 1) continue;
      int t = p / 3;
      float v1 = xr[r*132 + lane];
      float v2 = xr[r*132 + 64 + lane];
      float sum = v1 + v2;
      sum += __shfl_xor(sum,1); sum += __shfl_xor(sum,2); sum += __shfl_xor(sum,4);
      sum += __shfl_xor(sum,8); sum += __shfl_xor(sum,16); sum += __shfl_xor(sum,32);
      float mean = sum*(1.0f/128.0f);
      float d1 = v1-mean, d2 = v2-mean;
      float var = d1*d1 + d2*d2;
      var += __shfl_xor(var,1); var += __shfl_xor(var,2); var += __shfl_xor(var,4);
      var += __shfl_xor(var,8); var += __shfl_xor(var,16); var += __shfl_xor(var,32);
      float rstd = rsqrtf(var*(1.0f/128.0f) + 1e-5f);
      float h1 = d1*rstd*lnfg[lane]    + lnfb[lane];
      float h2v= d2*rstd*lnfg[lane+64] + lnfb[lane+64];
      #pragma unroll
      for (int o=0; o<NV; ++o){
        float sdot = h1*hw[o*128+lane] + h2v*hw[o*128+lane+64];
        sdot += __shfl_xor(sdot,1); sdot += __shfl_xor(sdot,2); sdot += __shfl_xor(sdot,4);
        sdot += __shfl_xor(sdot,8); sdot += __shfl_xor(sdot,16); sdot += __shfl_xor(sdot,32);
        if (lane == 0) out[(size_t)(bb2*NT+t)*NV + o] = sdot;
      }
    }
  }
}

// ===========================================================================
extern "C" void kernel_launch(void* const* d_in, const int* in_sizes, int n_in,
                              void* d_out, int out_size, void* d_ws, size_t ws_size,
                              hipStream_t stream)
{
  const float* states  = (const float*)d_in[0];
  const int*   actions = (const int*)  d_in[1];
  const float* rtgs    = (const float*)d_in[2];
  const int*   tsteps  = (const int*)  d_in[3];
  const float* conv_w  = (const float*)d_in[4];
  const float* ctok    = (const float*)d_in[5];
  const float* in_w    = (const float*)d_in[6];
  const float* in_b    = (const float*)d_in[7];
  const float* out_w   = (const float*)d_in[8];
  const float* out_b   = (const float*)d_in[9];
  const float* i1g     = (const float*)d_in[10];
  const float* i1b     = (const float*)d_in[11];
  const float* i2g     = (const float*)d_in[12];
  const float* i2b     = (const float*)d_in[13];
  const float* fw1     = (const float*)d_in[14];
  const float* fb1     = (const float*)d_in[15];
  const float* fw2     = (const float*)d_in[16];
  const float* fb2     = (const float*)d_in[17];
  const float* ret_w   = (const float*)d_in[18];
  const float* ret_b   = (const float*)d_in[19];
  const float* act_tab = (const float*)d_in[20];
  const float* pos_emb = (const float*)d_in[21];
  const float* gpos    = (const float*)d_in[22];
  const float* ln1g    = (const float*)d_in[23];
  const float* ln1b    = (const float*)d_in[24];
  const float* Wq      = (const float*)d_in[25];
  const float* bq      = (const float*)d_in[26];
  const float* Wk      = (const float*)d_in[27];
  const float* bk      = (const float*)d_in[28];
  const float* Wv      = (const float*)d_in[29];
  const float* bv      = (const float*)d_in[30];
  const float* Wo      = (const float*)d_in[31];
  const float* bo      = (const float*)d_in[32];
  const float* ln2g    = (const float*)d_in[33];
  const float* ln2b    = (const float*)d_in[34];
  const float* W1      = (const float*)d_in[35];
  const float* b1      = (const float*)d_in[36];
  const float* W2      = (const float*)d_in[37];
  const float* b2      = (const float*)d_in[38];
  const float* lnfg    = (const float*)d_in[39];
  const float* lnfb    = (const float*)d_in[40];
  const float* head_w  = (const float*)d_in[41];

  char* w = (char*)d_ws;
  size_t off = 0;
  auto alloc = [&](size_t bytes)->char* {
    char* p = w + off; off += (bytes + 255) & ~(size_t)255; return p;
  };
  float*    part  = (float*)   alloc((size_t)NZ*NBT*EE*4);
  float*    x     = (float*)   alloc((size_t)NS*EE*4);
  ushort_t* xlnA  = (ushort_t*)alloc((size_t)NS*EE*2);
  ushort_t* xlnB  = (ushort_t*)alloc((size_t)NS*EE*2);
  ushort_t* yb    = (ushort_t*)alloc((size_t)NS*EE*2);
  ushort_t* cwb   = (ushort_t*)alloc((size_t)EE*KP*2);
  ushort_t* Wqkvb = (ushort_t*)alloc((size_t)NLY*384*128*2);
  ushort_t* Wob   = (ushort_t*)alloc((size_t)NLY*128*128*2);
  ushort_t* W1b   = (ushort_t*)alloc((size_t)NLY*512*128*2);
  ushort_t* W2b   = (ushort_t*)alloc((size_t)NLY*128*512*2);
  ushort_t* inwb  = (ushort_t*)alloc((size_t)384*128*2);
  ushort_t* outwb = (ushort_t*)alloc((size_t)128*128*2);
  ushort_t* f1wb  = (ushort_t*)alloc((size_t)128*128*2);
  ushort_t* f2wb  = (ushort_t*)alloc((size_t)128*128*2);
  float*    bqkv  = (float*)   alloc(NLY*384*4);
  (void)in_sizes; (void)n_in; (void)out_size; (void)ws_size;

  wcvt<<<4779,256,0,stream>>>(conv_w,Wq,Wk,Wv,Wo,W1,W2,
                              in_w,out_w,fw1,fw2, bq,bk,bv,
                              cwb,Wqkvb,Wob,W1b,W2b,
                              inwb,outwb,f1wb,f2wb, bqkv);
  patch_gemm<<<dim3(30,1,NZ),256,0,stream>>>(states, cwb, part);
  inner_tit<<<240,256,0,stream>>>(part, ctok, inwb, in_b, outwb, out_b,
                                  i1g,i1b,i2g,i2b, f1wb,fb1, f2wb,fb2,
                                  rtgs, actions, tsteps, ret_w, ret_b, act_tab,
                                  pos_emb, gpos, ln1g, ln1b, x, xlnA);
  for (int i=0;i<NLY;i++){
    ushort_t* xin  = (i & 1) ? xlnB : xlnA;
    ushort_t* xout = (i & 1) ? xlnA : xlnB;
    attn_fused<<<512,256,0,stream>>>(
      xin, Wqkvb+(size_t)i*49152, bqkv+(size_t)i*384, yb);
    if (i < NLY-1)
      ffn_fused<false><<<178,256,0,stream>>>(
        yb, Wob+(size_t)i*16384, bo+i*128, ln2g+i*128, ln2b+i*128,
        W1b+(size_t)i*65536, b1+i*512, W2b+(size_t)i*65536, b2+i*128, x,
        ln1g+(i+1)*128, ln1b+(i+1)*128, xout,
        nullptr, nullptr, nullptr, nullptr);
    else
      ffn_fused<true><<<178,256,0,stream>>>(
        yb, Wob+(size_t)i*16384, bo+i*128, ln2g+i*128, ln2b+i*128,
        W1b+(size_t)i*65536, b1+i*512, W2b+(size_t)i*65536, b2+i*128, x,
        nullptr, nullptr, nullptr,
        lnfg, lnfb, head_w, (float*)d_out);
  }
}